// Round 1
// baseline (1011.341 us; speedup 1.0000x reference)
//
#include <hip/hip_runtime.h>
#include <math.h>

// SCQ layer forward, f32 throughout.
// Pipeline:
//   1. Z = LN(inputs @ d_w + d_b)          (Z stored in d_out Zq slot)
//   2. S = I + C C^T (Woodbury, 256x256); Sinv via Newton-Schulz (8 it)
//   3. U = Sinv C ; Ainv = I - C^T U  (= (C^T C + I)^-1)
//   4. scores = Z @ C  (into d_out P slot) -> argmin -> assign
//   5. P_sol^T = Z @ U + Ainv[assign,:]    (overwrites P slot)
//   6. simplex-project rows in place (Michelot)
//   7. Zq = P @ C^T (overwrites Z slot; loss partials from (Zq-Z)^2)
//   8. column means -> perplexity/entropy; diversity from G = C^T C

#define M_ 32768
#define D_ 256
#define K_ 512

// ---------------- big GEMM: Out(MxN) = A(MxKd) @ B(KdxN) [+ epilogue] --------
// EPI: 0 none, 1 +bias[n], 2 +Ainv[assign[m],n], 3 loss ((Out-Zref)^2 partials)
template<int EPI>
__global__ __launch_bounds__(256)
void big_gemm(const float* __restrict__ A, const float* __restrict__ B,
              float* Out, int M, int N, int Kd,
              const float* __restrict__ bias,
              const float* __restrict__ AinvM, const int* __restrict__ assign,
              const float* Zref, float* __restrict__ lossPart)
{
    __shared__ float As[16][132];   // row stride 132 floats = 528B (16B-aligned)
    __shared__ float Bs[16][128];
    const int tid = threadIdx.x;
    const int tx = tid & 15, ty = tid >> 4;
    const int n0 = blockIdx.x * 128;
    const int m0 = blockIdx.y * 128;

    float acc[8][8];
#pragma unroll
    for (int i = 0; i < 8; ++i)
#pragma unroll
        for (int j = 0; j < 8; ++j) acc[i][j] = 0.f;

    const int ar = tid >> 1, ac = (tid & 1) * 8;
    const int br = tid >> 4, bc = (tid & 15) * 8;
    const float* Ap = A + (size_t)(m0 + ar) * Kd + ac;
    const float* Bp = B + (size_t)br * N + n0 + bc;

    for (int kb = 0; kb < Kd; kb += 16) {
        float4 a0 = *(const float4*)(Ap + kb);
        float4 a1 = *(const float4*)(Ap + kb + 4);
        float4 b0 = *(const float4*)(Bp + (size_t)kb * N);
        float4 b1 = *(const float4*)(Bp + (size_t)kb * N + 4);
        As[ac+0][ar] = a0.x; As[ac+1][ar] = a0.y; As[ac+2][ar] = a0.z; As[ac+3][ar] = a0.w;
        As[ac+4][ar] = a1.x; As[ac+5][ar] = a1.y; As[ac+6][ar] = a1.z; As[ac+7][ar] = a1.w;
        *(float4*)&Bs[br][bc]     = b0;
        *(float4*)&Bs[br][bc + 4] = b1;
        __syncthreads();
#pragma unroll
        for (int kk = 0; kk < 16; ++kk) {
            float4 av0 = *(const float4*)&As[kk][ty*4];
            float4 av1 = *(const float4*)&As[kk][64 + ty*4];
            float4 bv0 = *(const float4*)&Bs[kk][tx*4];
            float4 bv1 = *(const float4*)&Bs[kk][64 + tx*4];
            float a_[8] = {av0.x, av0.y, av0.z, av0.w, av1.x, av1.y, av1.z, av1.w};
            float b_[8] = {bv0.x, bv0.y, bv0.z, bv0.w, bv1.x, bv1.y, bv1.z, bv1.w};
#pragma unroll
            for (int i = 0; i < 8; ++i)
#pragma unroll
                for (int j = 0; j < 8; ++j)
                    acc[i][j] = fmaf(a_[i], b_[j], acc[i][j]);
        }
        __syncthreads();
    }

    float lsum = 0.f;
#pragma unroll
    for (int hi = 0; hi < 2; ++hi) {
#pragma unroll
        for (int i = 0; i < 4; ++i) {
            const int row = m0 + hi*64 + ty*4 + i;
            int am = 0;
            if (EPI == 2) am = assign[row];
#pragma unroll
            for (int hj = 0; hj < 2; ++hj) {
                const int col = n0 + hj*64 + tx*4;
                float4 v;
                v.x = acc[hi*4+i][hj*4+0];
                v.y = acc[hi*4+i][hj*4+1];
                v.z = acc[hi*4+i][hj*4+2];
                v.w = acc[hi*4+i][hj*4+3];
                if (EPI == 1) {
                    v.x += bias[col+0]; v.y += bias[col+1];
                    v.z += bias[col+2]; v.w += bias[col+3];
                } else if (EPI == 2) {
                    const float4 g = *(const float4*)(AinvM + (size_t)am * K_ + col);
                    v.x += g.x; v.y += g.y; v.z += g.z; v.w += g.w;
                } else if (EPI == 3) {
                    const float4 z = *(const float4*)(Zref + (size_t)row * N + col);
                    float dx = v.x - z.x, dy = v.y - z.y, dz = v.z - z.z, dw = v.w - z.w;
                    lsum += dx*dx + dy*dy + dz*dz + dw*dw;
                }
                *(float4*)(Out + (size_t)row * N + col) = v;
            }
        }
    }
    if (EPI == 3) {
        __shared__ float red[256];
        red[tid] = lsum;
        __syncthreads();
        for (int s = 128; s > 0; s >>= 1) {
            if (tid < s) red[tid] += red[tid + s];
            __syncthreads();
        }
        if (tid == 0) lossPart[blockIdx.y * gridDim.x + blockIdx.x] = red[0];
    }
}

// ---------------- small GEMM: 64x64 tiles -----------------------------------
// TRA=0: A is (M,Kd) row-major.  TRA=1: A is (Kd,M) row-major (Out = A^T B).
// B always (Kd,N) row-major.
// EPI: 0 none; 1: Out = 2*E - acc (Newton-Schulz); 2: Out = I - acc; 3: Out = acc + I
template<int TRA, int EPI>
__global__ __launch_bounds__(256)
void small_gemm(const float* __restrict__ A, const float* __restrict__ B,
                const float* __restrict__ E, float* __restrict__ Out,
                int M, int N, int Kd)
{
    __shared__ float As[16][68];
    __shared__ float Bs[16][68];
    const int tid = threadIdx.x;
    const int tx = tid & 15, ty = tid >> 4;
    const int n0 = blockIdx.x * 64, m0 = blockIdx.y * 64;
    float acc[4][4];
#pragma unroll
    for (int i = 0; i < 4; ++i)
#pragma unroll
        for (int j = 0; j < 4; ++j) acc[i][j] = 0.f;

    for (int kb = 0; kb < Kd; kb += 16) {
        if (TRA == 0) {
            const int ar2 = tid >> 2, ac2 = (tid & 3) * 4;
            float4 a = *(const float4*)(A + (size_t)(m0 + ar2) * Kd + kb + ac2);
            As[ac2+0][ar2] = a.x; As[ac2+1][ar2] = a.y;
            As[ac2+2][ar2] = a.z; As[ac2+3][ar2] = a.w;
        } else {
            const int ar2 = tid >> 4, ac2 = (tid & 15) * 4;
            float4 a = *(const float4*)(A + (size_t)(kb + ar2) * M + m0 + ac2);
            *(float4*)&As[ar2][ac2] = a;
        }
        {
            const int br2 = tid >> 4, bc2 = (tid & 15) * 4;
            float4 b = *(const float4*)(B + (size_t)(kb + br2) * N + n0 + bc2);
            *(float4*)&Bs[br2][bc2] = b;
        }
        __syncthreads();
#pragma unroll
        for (int kk = 0; kk < 16; ++kk) {
            float4 a4 = *(const float4*)&As[kk][ty*4];
            float4 b4 = *(const float4*)&Bs[kk][tx*4];
            float a_[4] = {a4.x, a4.y, a4.z, a4.w};
            float b_[4] = {b4.x, b4.y, b4.z, b4.w};
#pragma unroll
            for (int i = 0; i < 4; ++i)
#pragma unroll
                for (int j = 0; j < 4; ++j)
                    acc[i][j] = fmaf(a_[i], b_[j], acc[i][j]);
        }
        __syncthreads();
    }
#pragma unroll
    for (int i = 0; i < 4; ++i) {
        const int row = m0 + ty*4 + i;
#pragma unroll
        for (int j = 0; j < 4; ++j) {
            const int col = n0 + tx*4 + j;
            float v = acc[i][j];
            if (EPI == 1) v = 2.f * E[(size_t)row * N + col] - v;
            else if (EPI == 2) v = ((row == col) ? 1.f : 0.f) - v;
            else if (EPI == 3) v = v + ((row == col) ? 1.f : 0.f);
            Out[(size_t)row * N + col] = v;
        }
    }
}

// ---------------- LayerNorm (one row of 256 per block) + ||row||^2 ----------
__global__ __launch_bounds__(256)
void layernorm_kernel(float* X, const float* __restrict__ gamma,
                      const float* __restrict__ beta, float* __restrict__ zn2)
{
    __shared__ float red[256];
    const int m = blockIdx.x, t = threadIdx.x;
    float x = X[(size_t)m * D_ + t];
    red[t] = x; __syncthreads();
    for (int s = 128; s > 0; s >>= 1) { if (t < s) red[t] += red[t+s]; __syncthreads(); }
    const float mean = red[0] * (1.f / 256.f);
    __syncthreads();
    const float d = x - mean;
    red[t] = d * d; __syncthreads();
    for (int s = 128; s > 0; s >>= 1) { if (t < s) red[t] += red[t+s]; __syncthreads(); }
    const float var = red[0] * (1.f / 256.f);
    __syncthreads();
    const float y = gamma[t] * (d / sqrtf(var + 1e-5f)) + beta[t];
    X[(size_t)m * D_ + t] = y;
    red[t] = y * y; __syncthreads();
    for (int s = 128; s > 0; s >>= 1) { if (t < s) red[t] += red[t+s]; __syncthreads(); }
    if (t == 0) zn2[m] = red[0];
}

// ---------------- Ct = C^T ; column norms of C -------------------------------
__global__ void transpose_ct(const float* __restrict__ C, float* __restrict__ Ct)
{
    const int idx = blockIdx.x * 256 + threadIdx.x;   // over K_*D_
    const int k = idx >> 8, d = idx & 255;
    Ct[idx] = C[(size_t)d * K_ + k];
}

__global__ void cn2_kernel(const float* __restrict__ C, float* __restrict__ cn2)
{
    const int k = blockIdx.x * 256 + threadIdx.x;
    float s = 0.f;
    for (int d = 0; d < D_; ++d) { float c = C[(size_t)d * K_ + k]; s = fmaf(c, c, s); }
    cn2[k] = s;
}

// ---------------- ||S||_inf bound -> NS scale; X0 = c*I ----------------------
__global__ void rowsum_scal(const float* __restrict__ S, float* __restrict__ scal)
{
    __shared__ float red[256];
    const int t = threadIdx.x;
    float s = 0.f;
    for (int q = 0; q < D_; ++q) s += fabsf(S[(size_t)t * D_ + q]);
    red[t] = s; __syncthreads();
    for (int sh = 128; sh > 0; sh >>= 1) { if (t < sh) red[t] = fmaxf(red[t], red[t+sh]); __syncthreads(); }
    if (t == 0) scal[0] = 2.f / (1.f + red[0]);
}

__global__ void init_x0(float* __restrict__ X, const float* __restrict__ scal)
{
    const int i = blockIdx.x, j = threadIdx.x;
    X[(size_t)i * D_ + j] = (i == j) ? scal[0] : 0.f;
}

// ---------------- argmin over dists (one row per block) ----------------------
__global__ __launch_bounds__(256)
void argmin_kernel(const float* __restrict__ Sc, const float* __restrict__ cn2,
                   const float* __restrict__ zn2, int* __restrict__ assign)
{
    __shared__ float rv[256];
    __shared__ int   ri[256];
    const int m = blockIdx.x, t = threadIdx.x;
    const float zn = zn2[m];
    float best = 3.4e38f; int bi = 0;
    for (int k = t; k < K_; k += 256) {
        const float t1 = zn + cn2[k];               // matches ref eval order
        const float d  = t1 - 2.0f * Sc[(size_t)m * K_ + k];
        if (d < best) { best = d; bi = k; }         // ascending k -> first-min kept
    }
    rv[t] = best; ri[t] = bi; __syncthreads();
    for (int s = 128; s > 0; s >>= 1) {
        if (t < s) {
            const float ov = rv[t + s]; const int oi = ri[t + s];
            if (ov < rv[t] || (ov == rv[t] && oi < ri[t])) { rv[t] = ov; ri[t] = oi; }
        }
        __syncthreads();
    }
    if (t == 0) assign[m] = ri[0];
}

// ---------------- simplex projection, Michelot, one wave per row -------------
__global__ __launch_bounds__(256)
void project_kernel(float* P)
{
    const int wave = threadIdx.x >> 6;
    const int lane = threadIdx.x & 63;
    const int row = blockIdx.x * 4 + wave;
    const size_t base = (size_t)row * K_ + lane;
    float v[8];
#pragma unroll
    for (int j = 0; j < 8; ++j) v[j] = P[base + j * 64];

    float s = 0.f;
#pragma unroll
    for (int j = 0; j < 8; ++j) s += v[j];
    for (int off = 32; off > 0; off >>= 1) s += __shfl_xor(s, off);

    float theta = (s - 1.f) * (1.f / 512.f);
    int cnt = K_;
    for (int it = 0; it < K_; ++it) {
        float ls = 0.f; int lc = 0;
#pragma unroll
        for (int j = 0; j < 8; ++j)
            if (v[j] > theta) { ls += v[j]; ++lc; }
        for (int off = 32; off > 0; off >>= 1) {
            ls += __shfl_xor(ls, off);
            lc += __shfl_xor(lc, off);
        }
        if (lc == cnt) break;
        theta = (ls - 1.f) / (float)lc;
        cnt = lc;
    }
#pragma unroll
    for (int j = 0; j < 8; ++j) P[base + j * 64] = fmaxf(v[j] - theta, 0.f);
}

// ---------------- column partial sums of P (for p_j) -------------------------
__global__ __launch_bounds__(512)
void colsum_kernel(const float* __restrict__ P, float* __restrict__ part)
{
    const int k = threadIdx.x;          // 0..511
    const int b = blockIdx.x;           // 0..255, 128 rows each
    float s = 0.f;
    const size_t base = (size_t)b * 128 * K_ + k;
    for (int r = 0; r < 128; ++r) s += P[base + (size_t)r * K_];
    part[(size_t)b * K_ + k] = s;
}

// ---------------- finalize: perplexity, entropy, diversity, loss -------------
#define BLOCK_REDUCE_512(val, result) \
    red[t] = (val); __syncthreads(); \
    for (int s_ = 256; s_ > 0; s_ >>= 1) { if (t < s_) red[t] += red[t + s_]; __syncthreads(); } \
    result = red[0]; __syncthreads();

__global__ __launch_bounds__(512)
void finalize_kernel(const float* __restrict__ part, const float* __restrict__ G,
                     const float* __restrict__ cn2, const float* __restrict__ lossPart,
                     float* __restrict__ out_scal)
{
    __shared__ float red[512];
    __shared__ float sh_rsn[512];
    const int t = threadIdx.x;

    float praw = 0.f;
    for (int b = 0; b < 256; ++b) praw += part[b * K_ + t];
    const float pm = praw * (1.f / 32768.f);           // p_mean[k]
    sh_rsn[t] = 1.f / sqrtf(fmaxf(cn2[t], 1e-12f));
    __syncthreads();

    // perplexity
    const float pj = fminf(fmaxf(pm, 1e-10f), 1.0f);   // 1-1e-9 rounds to 1.0f
    float sp; BLOCK_REDUCE_512(pj, sp);
    const float pjn = pj / sp;
    float Hbits; BLOCK_REDUCE_512(-pjn * logf(pjn) / 0.69314718056f, Hbits);

    // entropy regularizer
    float spm; BLOCK_REDUCE_512(pm, spm);
    const float s2 = spm + 1e-5f;
    const float pmn = pm / s2;
    float ereg; BLOCK_REDUCE_512(-pmn * logf(pmn + 1e-5f), ereg);

    // diversity from G = C^T C
    float dsum = 0.f;
    for (int idx = t; idx < K_ * K_; idx += 512) {
        const int i = idx >> 9, j = idx & 511;
        if (i != j) dsum += fmaxf(G[idx] * sh_rsn[i] * sh_rsn[j], 0.f);
    }
    float divs; BLOCK_REDUCE_512(dsum, divs);
    const float divloss = divs * (1.f / 262144.f);

    // primary loss
    float lp = lossPart[t];                            // exactly 512 partials
    float prim; BLOCK_REDUCE_512(lp, prim);
    prim *= 1.f / 8388608.f;                           // /(M*D)

    if (t == 0) {
        out_scal[0] = prim + 0.5f * ereg + 0.5f * divloss;
        out_scal[1] = exp2f(Hbits);
    }
}

// ---------------- launch -----------------------------------------------------
extern "C" void kernel_launch(void* const* d_in, const int* in_sizes, int n_in,
                              void* d_out, int out_size, void* d_ws, size_t ws_size,
                              hipStream_t stream)
{
    const float* inputs = (const float*)d_in[0];
    const float* gamma  = (const float*)d_in[1];
    const float* beta   = (const float*)d_in[2];
    const float* C      = (const float*)d_in[3];   // (D,K)
    const float* d_w    = (const float*)d_in[4];   // (D,D)
    const float* d_b    = (const float*)d_in[5];   // (D,)

    float* out = (float*)d_out;
    float* Z = out;                                 // M*D slot (Z, later Zq)
    float* P = out + (size_t)M_ * D_;               // M*K slot (scores, later P)
    float* out_scal = P + (size_t)M_ * K_;          // loss, perplexity

    float* w = (float*)d_ws;
    float* Smat = w;     w += D_ * D_;
    float* Xa   = w;     w += D_ * D_;
    float* Xb   = w;     w += D_ * D_;
    float* Tb   = w;     w += D_ * D_;
    float* U    = w;     w += D_ * K_;
    float* Ainv = w;     w += K_ * K_;
    float* G    = w;     w += K_ * K_;
    float* Ct   = w;     w += K_ * D_;
    float* cn2  = w;     w += K_;
    float* zn2  = w;     w += M_;
    float* scal = w;     w += 16;
    float* part = w;     w += 256 * K_;
    float* lossPart = w; w += 512;
    int* assign = (int*)w;

    // 1. X = inputs @ d_w + d_b
    big_gemm<1><<<dim3(D_/128, M_/128), 256, 0, stream>>>(
        inputs, d_w, Z, M_, D_, D_, d_b, nullptr, nullptr, nullptr, nullptr);
    // 2. layernorm in place + ||z||^2
    layernorm_kernel<<<M_, 256, 0, stream>>>(Z, gamma, beta, zn2);
    // 3/4. C^T and column norms
    transpose_ct<<<(K_ * D_) / 256, 256, 0, stream>>>(C, Ct);
    cn2_kernel<<<K_ / 256, 256, 0, stream>>>(C, cn2);
    // 5. S = Ct^T Ct + I  (= C C^T + I)
    small_gemm<1, 3><<<dim3(D_/64, D_/64), 256, 0, stream>>>(Ct, Ct, nullptr, Smat, D_, D_, K_);
    // 6/7. NS init
    rowsum_scal<<<1, 256, 0, stream>>>(Smat, scal);
    init_x0<<<D_, D_, 0, stream>>>(Xa, scal);
    // 8. Newton-Schulz: X <- 2X - X S X
    float* Xc = Xa; float* Xn = Xb;
    for (int it = 0; it < 8; ++it) {
        small_gemm<0, 0><<<dim3(D_/64, D_/64), 256, 0, stream>>>(Smat, Xc, nullptr, Tb, D_, D_, D_);
        small_gemm<0, 1><<<dim3(D_/64, D_/64), 256, 0, stream>>>(Xc, Tb, Xc, Xn, D_, D_, D_);
        float* tmp = Xc; Xc = Xn; Xn = tmp;
    }
    // 9. U = Sinv @ C ; Ainv = I - C^T U ; G = C^T C
    small_gemm<0, 0><<<dim3(K_/64, D_/64), 256, 0, stream>>>(Xc, C, nullptr, U, D_, K_, D_);
    small_gemm<1, 2><<<dim3(K_/64, K_/64), 256, 0, stream>>>(C, U, nullptr, Ainv, K_, K_, D_);
    small_gemm<1, 0><<<dim3(K_/64, K_/64), 256, 0, stream>>>(C, C, nullptr, G, K_, K_, D_);
    // 10. scores = Z @ C -> argmin
    big_gemm<0><<<dim3(K_/128, M_/128), 256, 0, stream>>>(
        Z, C, P, M_, K_, D_, nullptr, nullptr, nullptr, nullptr, nullptr);
    argmin_kernel<<<M_, 256, 0, stream>>>(P, cn2, zn2, assign);
    // 11. P_sol^T = Z @ U + Ainv[assign,:]
    big_gemm<2><<<dim3(K_/128, M_/128), 256, 0, stream>>>(
        Z, U, P, M_, K_, D_, nullptr, Ainv, assign, nullptr, nullptr);
    // 12. simplex projection in place
    project_kernel<<<M_/4, 256, 0, stream>>>(P);
    // 13. column partial sums
    colsum_kernel<<<256, 512, 0, stream>>>(P, part);
    // 14. Zq = P @ Ct (reads Z elementwise, overwrites with Zq; loss partials)
    big_gemm<3><<<dim3(D_/128, M_/128), 256, 0, stream>>>(
        P, Ct, Z, M_, D_, K_, nullptr, nullptr, nullptr, Z, lossPart);
    // 15. scalars
    finalize_kernel<<<1, 512, 0, stream>>>(part, G, cn2, lossPart, out_scal);

    (void)in_sizes; (void)n_in; (void)out_size; (void)ws_size;
}

// Round 2
// 770.589 us; speedup vs baseline: 1.3124x; 1.3124x over previous
//
#include <hip/hip_runtime.h>
#include <math.h>

// SCQ layer forward, f32 throughout.
//   1. Z = LN(inputs @ d_w + d_b)   (fused dense+LN, Z in d_out Zq slot)
//   2. S = I + C C^T (Woodbury); Sinv via Newton-Schulz (6 it)
//   3. U = Sinv C ; Ainv = I - C^T U  (= (C^T C + I)^-1)
//   4. scores = Z @ C fused with per-tile partial argmin -> assign
//   5. P_sol^T = Z @ U + Ainv[assign,:]   (into d_out P slot)
//   6. simplex-project rows in place (Michelot)
//   7. Zq = P @ C^T (overwrites Z slot; loss partials)
//   8. diversity fused into G-GEMM epilogue; slim finalize

#define M_ 32768
#define D_ 256
#define K_ 512

// ---------------- big GEMM: Out(MxN) = A(MxKd) @ B(KdxN) [+ epilogue] --------
// EPI: 2 +Ainv[assign[m],n], 3 loss ((Out-Zref)^2 partials)
template<int EPI>
__global__ __launch_bounds__(256)
void big_gemm(const float* __restrict__ A, const float* __restrict__ B,
              float* Out, int M, int N, int Kd,
              const float* __restrict__ AinvM, const int* __restrict__ assign,
              const float* Zref, float* __restrict__ lossPart)
{
    __shared__ float As[16][132];
    __shared__ float Bs[16][128];
    const int tid = threadIdx.x;
    const int tx = tid & 15, ty = tid >> 4;
    const int n0 = blockIdx.x * 128;
    const int m0 = blockIdx.y * 128;

    float acc[8][8];
#pragma unroll
    for (int i = 0; i < 8; ++i)
#pragma unroll
        for (int j = 0; j < 8; ++j) acc[i][j] = 0.f;

    const int ar = tid >> 1, ac = (tid & 1) * 8;
    const int br = tid >> 4, bc = (tid & 15) * 8;
    const float* Ap = A + (size_t)(m0 + ar) * Kd + ac;
    const float* Bp = B + (size_t)br * N + n0 + bc;

    for (int kb = 0; kb < Kd; kb += 16) {
        float4 a0 = *(const float4*)(Ap + kb);
        float4 a1 = *(const float4*)(Ap + kb + 4);
        float4 b0 = *(const float4*)(Bp + (size_t)kb * N);
        float4 b1 = *(const float4*)(Bp + (size_t)kb * N + 4);
        As[ac+0][ar] = a0.x; As[ac+1][ar] = a0.y; As[ac+2][ar] = a0.z; As[ac+3][ar] = a0.w;
        As[ac+4][ar] = a1.x; As[ac+5][ar] = a1.y; As[ac+6][ar] = a1.z; As[ac+7][ar] = a1.w;
        *(float4*)&Bs[br][bc]     = b0;
        *(float4*)&Bs[br][bc + 4] = b1;
        __syncthreads();
#pragma unroll
        for (int kk = 0; kk < 16; ++kk) {
            float4 av0 = *(const float4*)&As[kk][ty*4];
            float4 av1 = *(const float4*)&As[kk][64 + ty*4];
            float4 bv0 = *(const float4*)&Bs[kk][tx*4];
            float4 bv1 = *(const float4*)&Bs[kk][64 + tx*4];
            float a_[8] = {av0.x, av0.y, av0.z, av0.w, av1.x, av1.y, av1.z, av1.w};
            float b_[8] = {bv0.x, bv0.y, bv0.z, bv0.w, bv1.x, bv1.y, bv1.z, bv1.w};
#pragma unroll
            for (int i = 0; i < 8; ++i)
#pragma unroll
                for (int j = 0; j < 8; ++j)
                    acc[i][j] = fmaf(a_[i], b_[j], acc[i][j]);
        }
        __syncthreads();
    }

    float lsum = 0.f;
#pragma unroll
    for (int hi = 0; hi < 2; ++hi) {
#pragma unroll
        for (int i = 0; i < 4; ++i) {
            const int row = m0 + hi*64 + ty*4 + i;
            int am = 0;
            if (EPI == 2) am = assign[row];
#pragma unroll
            for (int hj = 0; hj < 2; ++hj) {
                const int col = n0 + hj*64 + tx*4;
                float4 v;
                v.x = acc[hi*4+i][hj*4+0];
                v.y = acc[hi*4+i][hj*4+1];
                v.z = acc[hi*4+i][hj*4+2];
                v.w = acc[hi*4+i][hj*4+3];
                if (EPI == 2) {
                    const float4 g = *(const float4*)(AinvM + (size_t)am * K_ + col);
                    v.x += g.x; v.y += g.y; v.z += g.z; v.w += g.w;
                } else if (EPI == 3) {
                    const float4 z = *(const float4*)(Zref + (size_t)row * N + col);
                    float dx = v.x - z.x, dy = v.y - z.y, dz = v.z - z.z, dw = v.w - z.w;
                    lsum += dx*dx + dy*dy + dz*dz + dw*dw;
                }
                *(float4*)(Out + (size_t)row * N + col) = v;
            }
        }
    }
    if (EPI == 3) {
        __shared__ float red[256];
        red[tid] = lsum;
        __syncthreads();
        for (int s = 128; s > 0; s >>= 1) {
            if (tid < s) red[tid] += red[tid + s];
            __syncthreads();
        }
        if (tid == 0) lossPart[blockIdx.y * gridDim.x + blockIdx.x] = red[0];
    }
}

// -------- score GEMM (Z @ C) with fused per-tile partial argmin -------------
__global__ __launch_bounds__(256)
void score_argmin_gemm(const float* __restrict__ A, const float* __restrict__ B,
                       const float* __restrict__ cn2, const float* __restrict__ zn2,
                       float* __restrict__ PV, int* __restrict__ PI)
{
    // A: Z (M_,256), B: C (256,512); tile 128x128; grid (4, 256)
    __shared__ float As[16][132];
    __shared__ float Bs[16][128];
    __shared__ float sval[128][17];
    __shared__ int   sidx[128][17];
    const int tid = threadIdx.x;
    const int tx = tid & 15, ty = tid >> 4;
    const int n0 = blockIdx.x * 128;
    const int m0 = blockIdx.y * 128;

    float acc[8][8];
#pragma unroll
    for (int i = 0; i < 8; ++i)
#pragma unroll
        for (int j = 0; j < 8; ++j) acc[i][j] = 0.f;

    const int ar = tid >> 1, ac = (tid & 1) * 8;
    const int br = tid >> 4, bc = (tid & 15) * 8;
    const float* Ap = A + (size_t)(m0 + ar) * D_ + ac;
    const float* Bp = B + (size_t)br * K_ + n0 + bc;

    for (int kb = 0; kb < D_; kb += 16) {
        float4 a0 = *(const float4*)(Ap + kb);
        float4 a1 = *(const float4*)(Ap + kb + 4);
        float4 b0 = *(const float4*)(Bp + (size_t)kb * K_);
        float4 b1 = *(const float4*)(Bp + (size_t)kb * K_ + 4);
        As[ac+0][ar] = a0.x; As[ac+1][ar] = a0.y; As[ac+2][ar] = a0.z; As[ac+3][ar] = a0.w;
        As[ac+4][ar] = a1.x; As[ac+5][ar] = a1.y; As[ac+6][ar] = a1.z; As[ac+7][ar] = a1.w;
        *(float4*)&Bs[br][bc]     = b0;
        *(float4*)&Bs[br][bc + 4] = b1;
        __syncthreads();
#pragma unroll
        for (int kk = 0; kk < 16; ++kk) {
            float4 av0 = *(const float4*)&As[kk][ty*4];
            float4 av1 = *(const float4*)&As[kk][64 + ty*4];
            float4 bv0 = *(const float4*)&Bs[kk][tx*4];
            float4 bv1 = *(const float4*)&Bs[kk][64 + tx*4];
            float a_[8] = {av0.x, av0.y, av0.z, av0.w, av1.x, av1.y, av1.z, av1.w};
            float b_[8] = {bv0.x, bv0.y, bv0.z, bv0.w, bv1.x, bv1.y, bv1.z, bv1.w};
#pragma unroll
            for (int i = 0; i < 8; ++i)
#pragma unroll
                for (int j = 0; j < 8; ++j)
                    acc[i][j] = fmaf(a_[i], b_[j], acc[i][j]);
        }
        __syncthreads();
    }

    // per-row partial argmin of dist = (zn2[row] + cn2[col]) - 2*score
#pragma unroll
    for (int hi = 0; hi < 2; ++hi) {
#pragma unroll
        for (int i = 0; i < 4; ++i) {
            const int rl = hi*64 + ty*4 + i;
            const float zr = zn2[m0 + rl];
            float best = 3.4e38f; int bi = 0x7fffffff;
#pragma unroll
            for (int hj = 0; hj < 2; ++hj) {
#pragma unroll
                for (int j = 0; j < 4; ++j) {
                    const int col = n0 + hj*64 + tx*4 + j;
                    const float t1 = zr + cn2[col];
                    const float d  = t1 - 2.0f * acc[hi*4+i][hj*4+j];
                    if (d < best) { best = d; bi = col; }   // ascending col
                }
            }
            sval[rl][tx] = best; sidx[rl][tx] = bi;
        }
    }
    __syncthreads();
    if (tid < 128) {
        float best = sval[tid][0]; int bi = sidx[tid][0];
#pragma unroll
        for (int t = 1; t < 16; ++t) {
            const float v = sval[tid][t]; const int ix = sidx[tid][t];
            if (v < best || (v == best && ix < bi)) { best = v; bi = ix; }
        }
        PV[(size_t)(m0 + tid) * 4 + blockIdx.x] = best;
        PI[(size_t)(m0 + tid) * 4 + blockIdx.x] = bi;
    }
}

__global__ void argmin_reduce(const float* __restrict__ PV, const int* __restrict__ PI,
                              int* __restrict__ assign)
{
    const int m = blockIdx.x * 256 + threadIdx.x;
    float best = PV[(size_t)m * 4]; int bi = PI[(size_t)m * 4];
#pragma unroll
    for (int nb = 1; nb < 4; ++nb) {
        const float v = PV[(size_t)m * 4 + nb]; const int ix = PI[(size_t)m * 4 + nb];
        if (v < best || (v == best && ix < bi)) { best = v; bi = ix; }
    }
    assign[m] = bi;
}

// ---------------- fused dense (64x256 tile, full width) + LayerNorm ----------
__global__ __launch_bounds__(256)
void dense_ln_kernel(const float* __restrict__ A, const float* __restrict__ Bw,
                     const float* __restrict__ bias, const float* __restrict__ gamma,
                     const float* __restrict__ beta, float* __restrict__ Z,
                     float* __restrict__ zn2)
{
    __shared__ float As[16][68];
    __shared__ float Bs[16][256];
    __shared__ float rred[64][17];
    __shared__ float rstat[64];
    const int tid = threadIdx.x, tx = tid & 15, ty = tid >> 4;
    const int m0 = blockIdx.x * 64;
    float acc[4][16];
#pragma unroll
    for (int i = 0; i < 4; ++i)
#pragma unroll
        for (int j = 0; j < 16; ++j) acc[i][j] = 0.f;

    const int ar = tid >> 2, ac = (tid & 3) * 4;
    const int br = tid >> 4, bc = (tid & 15) * 16;
    for (int kb = 0; kb < 256; kb += 16) {
        float4 a = *(const float4*)(A + (size_t)(m0 + ar) * 256 + kb + ac);
        As[ac+0][ar] = a.x; As[ac+1][ar] = a.y; As[ac+2][ar] = a.z; As[ac+3][ar] = a.w;
#pragma unroll
        for (int q = 0; q < 4; ++q)
            *(float4*)&Bs[br][bc + q*4] =
                *(const float4*)(Bw + (size_t)(kb + br) * 256 + bc + q*4);
        __syncthreads();
#pragma unroll
        for (int kk = 0; kk < 16; ++kk) {
            float4 a4 = *(const float4*)&As[kk][ty*4];
            float av[4] = {a4.x, a4.y, a4.z, a4.w};
            float bv[16];
#pragma unroll
            for (int q = 0; q < 4; ++q) {
                float4 b4 = *(const float4*)&Bs[kk][q*64 + tx*4];
                bv[q*4+0] = b4.x; bv[q*4+1] = b4.y; bv[q*4+2] = b4.z; bv[q*4+3] = b4.w;
            }
#pragma unroll
            for (int i = 0; i < 4; ++i)
#pragma unroll
                for (int j = 0; j < 16; ++j)
                    acc[i][j] = fmaf(av[i], bv[j], acc[i][j]);
        }
        __syncthreads();
    }

    // + bias
    float bcol[16];
#pragma unroll
    for (int q = 0; q < 4; ++q) {
        float4 b4 = *(const float4*)(bias + q*64 + tx*4);
        bcol[q*4+0] = b4.x; bcol[q*4+1] = b4.y; bcol[q*4+2] = b4.z; bcol[q*4+3] = b4.w;
    }
#pragma unroll
    for (int i = 0; i < 4; ++i)
#pragma unroll
        for (int j = 0; j < 16; ++j) acc[i][j] += bcol[j];

    // mean
#pragma unroll
    for (int i = 0; i < 4; ++i) {
        float s = 0.f;
#pragma unroll
        for (int j = 0; j < 16; ++j) s += acc[i][j];
        rred[ty*4+i][tx] = s;
    }
    __syncthreads();
    if (tid < 64) {
        float s = 0.f;
#pragma unroll
        for (int t = 0; t < 16; ++t) s += rred[tid][t];
        rstat[tid] = s * (1.f / 256.f);
    }
    __syncthreads();
    float mean_[4];
#pragma unroll
    for (int i = 0; i < 4; ++i) mean_[i] = rstat[ty*4+i];

    // var
#pragma unroll
    for (int i = 0; i < 4; ++i) {
        float s = 0.f;
#pragma unroll
        for (int j = 0; j < 16; ++j) { float d = acc[i][j] - mean_[i]; s += d * d; }
        rred[ty*4+i][tx] = s;
    }
    __syncthreads();
    if (tid < 64) {
        float s = 0.f;
#pragma unroll
        for (int t = 0; t < 16; ++t) s += rred[tid][t];
        rstat[tid] = s * (1.f / 256.f);
    }
    __syncthreads();
    float rstd_[4];
#pragma unroll
    for (int i = 0; i < 4; ++i) rstd_[i] = sqrtf(rstat[ty*4+i] + 1e-5f);

    float gam[16], bet[16];
#pragma unroll
    for (int q = 0; q < 4; ++q) {
        float4 g4 = *(const float4*)(gamma + q*64 + tx*4);
        float4 e4 = *(const float4*)(beta  + q*64 + tx*4);
        gam[q*4+0] = g4.x; gam[q*4+1] = g4.y; gam[q*4+2] = g4.z; gam[q*4+3] = g4.w;
        bet[q*4+0] = e4.x; bet[q*4+1] = e4.y; bet[q*4+2] = e4.z; bet[q*4+3] = e4.w;
    }
#pragma unroll
    for (int i = 0; i < 4; ++i)
#pragma unroll
        for (int j = 0; j < 16; ++j) {
            const float d = acc[i][j] - mean_[i];
            acc[i][j] = gam[j] * (d / rstd_[i]) + bet[j];
        }

    // zn2 = sum y^2
#pragma unroll
    for (int i = 0; i < 4; ++i) {
        float s = 0.f;
#pragma unroll
        for (int j = 0; j < 16; ++j) s += acc[i][j] * acc[i][j];
        rred[ty*4+i][tx] = s;
    }
    __syncthreads();
    if (tid < 64) {
        float s = 0.f;
#pragma unroll
        for (int t = 0; t < 16; ++t) s += rred[tid][t];
        zn2[m0 + tid] = s;
    }

    // store Z
#pragma unroll
    for (int i = 0; i < 4; ++i) {
        const int row = m0 + ty*4 + i;
#pragma unroll
        for (int q = 0; q < 4; ++q) {
            float4 v;
            v.x = acc[i][q*4+0]; v.y = acc[i][q*4+1];
            v.z = acc[i][q*4+2]; v.w = acc[i][q*4+3];
            *(float4*)(Z + (size_t)row * 256 + q*64 + tx*4) = v;
        }
    }
}

// ---------------- small GEMM: 64x64 tiles -----------------------------------
// TRA=0: A is (M,Kd).  TRA=1: A is (Kd,M) (Out = A^T B).  B is (Kd,N).
// EPI: 0 none; 1: Out = 2*E - acc (NS); 2: Out = I - acc; 3: Out = acc + I;
//      4: no store, diversity partial sum from acc (G tile) -> divPart
template<int TRA, int EPI>
__global__ __launch_bounds__(256)
void small_gemm(const float* __restrict__ A, const float* __restrict__ B,
                const float* __restrict__ E, float* __restrict__ Out,
                int M, int N, int Kd,
                const float* __restrict__ cn2, float* __restrict__ divPart)
{
    __shared__ float As[16][68];
    __shared__ float Bs[16][68];
    __shared__ float red2[256];
    const int tid = threadIdx.x;
    const int tx = tid & 15, ty = tid >> 4;
    const int n0 = blockIdx.x * 64, m0 = blockIdx.y * 64;
    float acc[4][4];
#pragma unroll
    for (int i = 0; i < 4; ++i)
#pragma unroll
        for (int j = 0; j < 4; ++j) acc[i][j] = 0.f;

    for (int kb = 0; kb < Kd; kb += 16) {
        if (TRA == 0) {
            const int ar2 = tid >> 2, ac2 = (tid & 3) * 4;
            float4 a = *(const float4*)(A + (size_t)(m0 + ar2) * Kd + kb + ac2);
            As[ac2+0][ar2] = a.x; As[ac2+1][ar2] = a.y;
            As[ac2+2][ar2] = a.z; As[ac2+3][ar2] = a.w;
        } else {
            const int ar2 = tid >> 4, ac2 = (tid & 15) * 4;
            float4 a = *(const float4*)(A + (size_t)(kb + ar2) * M + m0 + ac2);
            *(float4*)&As[ar2][ac2] = a;
        }
        {
            const int br2 = tid >> 4, bc2 = (tid & 15) * 4;
            float4 b = *(const float4*)(B + (size_t)(kb + br2) * N + n0 + bc2);
            *(float4*)&Bs[br2][bc2] = b;
        }
        __syncthreads();
#pragma unroll
        for (int kk = 0; kk < 16; ++kk) {
            float4 a4 = *(const float4*)&As[kk][ty*4];
            float4 b4 = *(const float4*)&Bs[kk][tx*4];
            float a_[4] = {a4.x, a4.y, a4.z, a4.w};
            float b_[4] = {b4.x, b4.y, b4.z, b4.w};
#pragma unroll
            for (int i = 0; i < 4; ++i)
#pragma unroll
                for (int j = 0; j < 4; ++j)
                    acc[i][j] = fmaf(a_[i], b_[j], acc[i][j]);
        }
        __syncthreads();
    }
    if (EPI == 4) {
        float dsum = 0.f;
#pragma unroll
        for (int i = 0; i < 4; ++i) {
            const int row = m0 + ty*4 + i;
            const float ri = 1.f / sqrtf(fmaxf(cn2[row], 1e-12f));
#pragma unroll
            for (int j = 0; j < 4; ++j) {
                const int col = n0 + tx*4 + j;
                if (row != col) {
                    const float rj = 1.f / sqrtf(fmaxf(cn2[col], 1e-12f));
                    dsum += fmaxf(acc[i][j] * ri * rj, 0.f);
                }
            }
        }
        red2[tid] = dsum;
        __syncthreads();
        for (int s = 128; s > 0; s >>= 1) {
            if (tid < s) red2[tid] += red2[tid + s];
            __syncthreads();
        }
        if (tid == 0) divPart[blockIdx.y * gridDim.x + blockIdx.x] = red2[0];
        return;
    }
#pragma unroll
    for (int i = 0; i < 4; ++i) {
        const int row = m0 + ty*4 + i;
#pragma unroll
        for (int j = 0; j < 4; ++j) {
            const int col = n0 + tx*4 + j;
            float v = acc[i][j];
            if (EPI == 1) v = 2.f * E[(size_t)row * N + col] - v;
            else if (EPI == 2) v = ((row == col) ? 1.f : 0.f) - v;
            else if (EPI == 3) v = v + ((row == col) ? 1.f : 0.f);
            Out[(size_t)row * N + col] = v;
        }
    }
}

// ---------------- Ct = C^T ; column norms of C -------------------------------
__global__ void transpose_ct(const float* __restrict__ C, float* __restrict__ Ct)
{
    const int idx = blockIdx.x * 256 + threadIdx.x;
    const int k = idx >> 8, d = idx & 255;
    Ct[idx] = C[(size_t)d * K_ + k];
}

__global__ void cn2_kernel(const float* __restrict__ C, float* __restrict__ cn2)
{
    const int k = blockIdx.x * 256 + threadIdx.x;
    float s = 0.f;
    for (int d = 0; d < D_; ++d) { float c = C[(size_t)d * K_ + k]; s = fmaf(c, c, s); }
    cn2[k] = s;
}

// ------------- ||S||_inf (via symmetry: column sums) -> X0 = c*I -------------
__global__ void scal_init_kernel(const float* __restrict__ S, float* __restrict__ X)
{
    __shared__ float red[256];
    const int t = threadIdx.x;
    float s = 0.f;
    for (int q = 0; q < D_; ++q) s += fabsf(S[(size_t)q * D_ + t]);  // coalesced
    red[t] = s; __syncthreads();
    for (int sh = 128; sh > 0; sh >>= 1) {
        if (t < sh) red[t] = fmaxf(red[t], red[t + sh]);
        __syncthreads();
    }
    const float c = 2.f / (1.f + red[0]);
    for (int idx = t; idx < D_ * D_; idx += 256) {
        const int i = idx >> 8, j = idx & 255;
        X[idx] = (i == j) ? c : 0.f;
    }
}

// ---------------- simplex projection, Michelot, one wave per row -------------
__global__ __launch_bounds__(256)
void project_kernel(float* P)
{
    const int wave = threadIdx.x >> 6;
    const int lane = threadIdx.x & 63;
    const int row = blockIdx.x * 4 + wave;
    const size_t base = (size_t)row * K_ + lane;
    float v[8];
#pragma unroll
    for (int j = 0; j < 8; ++j) v[j] = P[base + j * 64];

    float s = 0.f;
#pragma unroll
    for (int j = 0; j < 8; ++j) s += v[j];
    for (int off = 32; off > 0; off >>= 1) s += __shfl_xor(s, off);

    float theta = (s - 1.f) * (1.f / 512.f);
    int cnt = K_;
    for (int it = 0; it < K_; ++it) {
        float ls = 0.f; int lc = 0;
#pragma unroll
        for (int j = 0; j < 8; ++j)
            if (v[j] > theta) { ls += v[j]; ++lc; }
        for (int off = 32; off > 0; off >>= 1) {
            ls += __shfl_xor(ls, off);
            lc += __shfl_xor(lc, off);
        }
        if (lc == cnt) break;
        theta = (ls - 1.f) / (float)lc;
        cnt = lc;
    }
#pragma unroll
    for (int j = 0; j < 8; ++j) P[base + j * 64] = fmaxf(v[j] - theta, 0.f);
}

// ---------------- column partial sums of P (for p_j) -------------------------
__global__ __launch_bounds__(512)
void colsum_kernel(const float* __restrict__ P, float* __restrict__ part)
{
    const int k = threadIdx.x;
    const int b = blockIdx.x;
    float s = 0.f;
    const size_t base = (size_t)b * 128 * K_ + k;
    for (int r = 0; r < 128; ++r) s += P[base + (size_t)r * K_];
    part[(size_t)b * K_ + k] = s;
}

// ---------------- finalize (slim): scalars only ------------------------------
#define BLOCK_REDUCE_512(val, result) \
    red[t] = (val); __syncthreads(); \
    for (int s_ = 256; s_ > 0; s_ >>= 1) { if (t < s_) red[t] += red[t + s_]; __syncthreads(); } \
    result = red[0]; __syncthreads();

__global__ __launch_bounds__(512)
void finalize_kernel(const float* __restrict__ part, const float* __restrict__ divPart,
                     const float* __restrict__ lossPart, float* __restrict__ out_scal)
{
    __shared__ float red[512];
    const int t = threadIdx.x;

    float praw = 0.f;
    for (int b = 0; b < 256; ++b) praw += part[b * K_ + t];
    const float pm = praw * (1.f / 32768.f);

    // perplexity
    const float pj = fminf(fmaxf(pm, 1e-10f), 1.0f);
    float sp; BLOCK_REDUCE_512(pj, sp);
    const float pjn = pj / sp;
    float Hbits; BLOCK_REDUCE_512(-pjn * logf(pjn) / 0.69314718056f, Hbits);

    // entropy regularizer
    float spm; BLOCK_REDUCE_512(pm, spm);
    const float s2 = spm + 1e-5f;
    const float pmn = pm / s2;
    float ereg; BLOCK_REDUCE_512(-pmn * logf(pmn + 1e-5f), ereg);

    // diversity (64 partials from G-GEMM epilogue)
    float dv = (t < 64) ? divPart[t] : 0.f;
    float divs; BLOCK_REDUCE_512(dv, divs);
    const float divloss = divs * (1.f / 262144.f);

    // primary loss (512 partials)
    float lp = lossPart[t];
    float prim; BLOCK_REDUCE_512(lp, prim);
    prim *= 1.f / 8388608.f;

    if (t == 0) {
        out_scal[0] = prim + 0.5f * ereg + 0.5f * divloss;
        out_scal[1] = exp2f(Hbits);
    }
}

// ---------------- launch -----------------------------------------------------
extern "C" void kernel_launch(void* const* d_in, const int* in_sizes, int n_in,
                              void* d_out, int out_size, void* d_ws, size_t ws_size,
                              hipStream_t stream)
{
    const float* inputs = (const float*)d_in[0];
    const float* gamma  = (const float*)d_in[1];
    const float* beta   = (const float*)d_in[2];
    const float* C      = (const float*)d_in[3];   // (D,K)
    const float* d_w    = (const float*)d_in[4];   // (D,D)
    const float* d_b    = (const float*)d_in[5];   // (D,)

    float* out = (float*)d_out;
    float* Z = out;                                 // M*D slot (Z, later Zq)
    float* P = out + (size_t)M_ * D_;               // M*K slot (P_sol -> P_proj)
    float* out_scal = P + (size_t)M_ * K_;          // loss, perplexity

    float* w = (float*)d_ws;
    float* Smat = w;     w += D_ * D_;
    float* Xa   = w;     w += D_ * D_;
    float* Xb   = w;     w += D_ * D_;
    float* Tb   = w;     w += D_ * D_;
    float* U    = w;     w += D_ * K_;
    float* Ainv = w;     w += K_ * K_;
    float* Ct   = w;     w += K_ * D_;
    float* cn2  = w;     w += K_;
    float* zn2  = w;     w += M_;
    float* part = w;     w += 256 * K_;
    float* lossPart = w; w += 512;
    float* divPart  = w; w += 64;
    float* PV   = w;     w += M_ * 4;
    int* PI     = (int*)w; w += M_ * 4;
    int* assign = (int*)w;

    // 1. Z = LN(inputs @ d_w + d_b), zn2
    dense_ln_kernel<<<M_/64, 256, 0, stream>>>(inputs, d_w, d_b, gamma, beta, Z, zn2);
    // 2. C^T and column norms
    transpose_ct<<<(K_ * D_) / 256, 256, 0, stream>>>(C, Ct);
    cn2_kernel<<<K_ / 256, 256, 0, stream>>>(C, cn2);
    // 3. S = C C^T + I
    small_gemm<1, 3><<<dim3(D_/64, D_/64), 256, 0, stream>>>(Ct, Ct, nullptr, Smat, D_, D_, K_, nullptr, nullptr);
    // 4. NS init (fused scale + X0)
    scal_init_kernel<<<1, 256, 0, stream>>>(Smat, Xa);
    // 5. Newton-Schulz x6: X <- 2X - X S X
    float* Xc = Xa; float* Xn = Xb;
    for (int it = 0; it < 6; ++it) {
        small_gemm<0, 0><<<dim3(D_/64, D_/64), 256, 0, stream>>>(Smat, Xc, nullptr, Tb, D_, D_, D_, nullptr, nullptr);
        small_gemm<0, 1><<<dim3(D_/64, D_/64), 256, 0, stream>>>(Xc, Tb, Xc, Xn, D_, D_, D_, nullptr, nullptr);
        float* tmp = Xc; Xc = Xn; Xn = tmp;
    }
    // 6. U = Sinv C ; Ainv = I - C^T U ; diversity from G = C^T C (no store)
    small_gemm<0, 0><<<dim3(K_/64, D_/64), 256, 0, stream>>>(Xc, C, nullptr, U, D_, K_, D_, nullptr, nullptr);
    small_gemm<1, 2><<<dim3(K_/64, K_/64), 256, 0, stream>>>(C, U, nullptr, Ainv, K_, K_, D_, nullptr, nullptr);
    small_gemm<1, 4><<<dim3(K_/64, K_/64), 256, 0, stream>>>(C, C, nullptr, nullptr, K_, K_, D_, cn2, divPart);
    // 7. scores = Z @ C with fused partial argmin -> assign
    score_argmin_gemm<<<dim3(K_/128, M_/128), 256, 0, stream>>>(Z, C, cn2, zn2, PV, PI);
    argmin_reduce<<<M_/256, 256, 0, stream>>>(PV, PI, assign);
    // 8. P_sol^T = Z @ U + Ainv[assign,:]
    big_gemm<2><<<dim3(K_/128, M_/128), 256, 0, stream>>>(
        Z, U, P, M_, K_, D_, Ainv, assign, nullptr, nullptr);
    // 9. simplex projection in place
    project_kernel<<<M_/4, 256, 0, stream>>>(P);
    // 10. column partial sums
    colsum_kernel<<<256, 512, 0, stream>>>(P, part);
    // 11. Zq = P @ Ct (reads Z, overwrites with Zq; loss partials)
    big_gemm<3><<<dim3(D_/128, M_/128), 256, 0, stream>>>(
        P, Ct, Z, M_, D_, K_, nullptr, nullptr, Z, lossPart);
    // 12. scalars
    finalize_kernel<<<1, 512, 0, stream>>>(part, divPart, lossPart, out_scal);

    (void)in_sizes; (void)n_in; (void)out_size; (void)ws_size;
}

// Round 3
// 597.570 us; speedup vs baseline: 1.6924x; 1.2895x over previous
//
#include <hip/hip_runtime.h>
#include <math.h>

// SCQ layer forward.
//   argmin-critical chain (dense+LN, score GEMM) stays f32.
//   post-argmin GEMMs (P_sol, Zq) use split-bf16 (hi+lo) x3 MFMA.

#define M_ 32768
#define D_ 256
#define K_ 512

typedef short bf16x8 __attribute__((ext_vector_type(8)));
typedef unsigned short u16x8 __attribute__((ext_vector_type(8)));
typedef float f32x4 __attribute__((ext_vector_type(4)));

#define LSTR 56   // LDS row stride (ushorts): 112B, 16B-aligned, 2-way-free reads

// split 16 consecutive f32 into bf16 hi/lo planes (truncation split)
__device__ inline void stage16(const float* __restrict__ g,
                               unsigned short* __restrict__ lh,
                               unsigned short* __restrict__ ll)
{
    unsigned short hi[16], lo[16];
#pragma unroll
    for (int q = 0; q < 4; ++q) {
        float4 v = ((const float4*)g)[q];
        float f[4] = {v.x, v.y, v.z, v.w};
#pragma unroll
        for (int e = 0; e < 4; ++e) {
            unsigned int u = __float_as_uint(f[e]);
            unsigned short h = (unsigned short)(u >> 16);
            float fh = __uint_as_float(((unsigned int)h) << 16);
            float r = f[e] - fh;
            unsigned short l = (unsigned short)(__float_as_uint(r) >> 16);
            hi[q*4+e] = h; lo[q*4+e] = l;
        }
    }
    *(u16x8*)lh       = *(u16x8*)hi;
    *(u16x8*)(lh + 8) = *(u16x8*)(hi + 8);
    *(u16x8*)ll       = *(u16x8*)lo;
    *(u16x8*)(ll + 8) = *(u16x8*)(lo + 8);
}

// ---- MFMA GEMM: Out(Mx N) = A(MxKd) @ Bt^T, Bt is (N x Kd) row-major -------
// EPI: 2 = +Ainv[assign[row],col] (psol, N=512); 3 = Zq + loss partials (N=256)
template<int EPI>
__global__ __launch_bounds__(256)
void mfma_gemm(const float* __restrict__ A, const float* __restrict__ Bt,
               float* __restrict__ Out, int Kd, int N,
               const float* __restrict__ AinvM, const int* __restrict__ assign,
               const float* Zref, float* __restrict__ lossPart)
{
    __shared__ unsigned short sAh[128*LSTR], sAl[128*LSTR];
    __shared__ unsigned short sBh[128*LSTR], sBl[128*LSTR];
    __shared__ float red[256];
    const int tid = threadIdx.x;
    const int m0 = blockIdx.y * 128, n0 = blockIdx.x * 128;
    const int w = tid >> 6, lane = tid & 63;
    const int wr = (w & 1) * 64, wc = (w >> 1) * 64;
    const int cg = lane >> 4, cr = lane & 15;

    f32x4 acc[4][4];
    const f32x4 z4 = {0.f, 0.f, 0.f, 0.f};
#pragma unroll
    for (int i = 0; i < 4; ++i)
#pragma unroll
        for (int j = 0; j < 4; ++j) acc[i][j] = z4;

    const int sr = tid >> 1;
    const int sk = (tid & 1) * 16;
    const float* Ag = A  + (size_t)(m0 + sr) * Kd + sk;
    const float* Bg = Bt + (size_t)(n0 + sr) * Kd + sk;
    const int soff = sr * LSTR + sk;

    for (int kb = 0; kb < Kd; kb += 32) {
        stage16(Ag + kb, sAh + soff, sAl + soff);
        stage16(Bg + kb, sBh + soff, sBl + soff);
        __syncthreads();
        bf16x8 ah[4], al[4], bh[4], bl[4];
#pragma unroll
        for (int f = 0; f < 4; ++f) {
            const int ao = (wr + f*16 + cr) * LSTR + cg*8;
            ah[f] = *(const bf16x8*)&sAh[ao];
            al[f] = *(const bf16x8*)&sAl[ao];
            const int bo = (wc + f*16 + cr) * LSTR + cg*8;
            bh[f] = *(const bf16x8*)&sBh[bo];
            bl[f] = *(const bf16x8*)&sBl[bo];
        }
#pragma unroll
        for (int i = 0; i < 4; ++i)
#pragma unroll
            for (int j = 0; j < 4; ++j) {
                acc[i][j] = __builtin_amdgcn_mfma_f32_16x16x32_bf16(ah[i], bh[j], acc[i][j], 0, 0, 0);
                acc[i][j] = __builtin_amdgcn_mfma_f32_16x16x32_bf16(al[i], bh[j], acc[i][j], 0, 0, 0);
                acc[i][j] = __builtin_amdgcn_mfma_f32_16x16x32_bf16(ah[i], bl[j], acc[i][j], 0, 0, 0);
            }
        __syncthreads();
    }

    if (EPI == 2) {
#pragma unroll
        for (int i = 0; i < 4; ++i) {
#pragma unroll
            for (int q = 0; q < 4; ++q) {
                const int row = m0 + wr + i*16 + cg*4 + q;
                const int am = assign[row];
                const float* Arow = AinvM + (size_t)am * K_ + n0 + wc;
#pragma unroll
                for (int j = 0; j < 4; ++j)
                    Out[(size_t)row * N + n0 + wc + j*16 + cr] =
                        acc[i][j][q] + Arow[j*16 + cr];
            }
        }
    } else {
        float lsum = 0.f;
#pragma unroll
        for (int i = 0; i < 4; ++i) {
#pragma unroll
            for (int q = 0; q < 4; ++q) {
                const int row = m0 + wr + i*16 + cg*4 + q;
#pragma unroll
                for (int j = 0; j < 4; ++j) {
                    const int col = n0 + wc + j*16 + cr;
                    const float v = acc[i][j][q];
                    const float zv = Zref[(size_t)row * N + col];
                    const float d = v - zv;
                    lsum += d * d;
                    Out[(size_t)row * N + col] = v;
                }
            }
        }
        red[tid] = lsum;
        __syncthreads();
        for (int s = 128; s > 0; s >>= 1) {
            if (tid < s) red[tid] += red[tid + s];
            __syncthreads();
        }
        if (tid == 0) lossPart[blockIdx.y * gridDim.x + blockIdx.x] = red[0];
    }
}

// -------- score GEMM (Z @ C) f32, fused partial argmin (shuffle epilogue) ----
__global__ __launch_bounds__(256)
void score_argmin_gemm(const float* __restrict__ A, const float* __restrict__ B,
                       const float* __restrict__ cn2, const float* __restrict__ zn2,
                       float* __restrict__ PV, int* __restrict__ PI)
{
    __shared__ float As[16][132];
    __shared__ float Bs[16][128];
    const int tid = threadIdx.x;
    const int tx = tid & 15, ty = tid >> 4;
    const int n0 = blockIdx.x * 128;
    const int m0 = blockIdx.y * 128;

    float acc[8][8];
#pragma unroll
    for (int i = 0; i < 8; ++i)
#pragma unroll
        for (int j = 0; j < 8; ++j) acc[i][j] = 0.f;

    const int ar = tid >> 1, ac = (tid & 1) * 8;
    const int br = tid >> 4, bc = (tid & 15) * 8;
    const float* Ap = A + (size_t)(m0 + ar) * D_ + ac;
    const float* Bp = B + (size_t)br * K_ + n0 + bc;

    for (int kb = 0; kb < D_; kb += 16) {
        float4 a0 = *(const float4*)(Ap + kb);
        float4 a1 = *(const float4*)(Ap + kb + 4);
        float4 b0 = *(const float4*)(Bp + (size_t)kb * K_);
        float4 b1 = *(const float4*)(Bp + (size_t)kb * K_ + 4);
        As[ac+0][ar] = a0.x; As[ac+1][ar] = a0.y; As[ac+2][ar] = a0.z; As[ac+3][ar] = a0.w;
        As[ac+4][ar] = a1.x; As[ac+5][ar] = a1.y; As[ac+6][ar] = a1.z; As[ac+7][ar] = a1.w;
        *(float4*)&Bs[br][bc]     = b0;
        *(float4*)&Bs[br][bc + 4] = b1;
        __syncthreads();
#pragma unroll
        for (int kk = 0; kk < 16; ++kk) {
            float4 av0 = *(const float4*)&As[kk][ty*4];
            float4 av1 = *(const float4*)&As[kk][64 + ty*4];
            float4 bv0 = *(const float4*)&Bs[kk][tx*4];
            float4 bv1 = *(const float4*)&Bs[kk][64 + tx*4];
            float a_[8] = {av0.x, av0.y, av0.z, av0.w, av1.x, av1.y, av1.z, av1.w};
            float b_[8] = {bv0.x, bv0.y, bv0.z, bv0.w, bv1.x, bv1.y, bv1.z, bv1.w};
#pragma unroll
            for (int i = 0; i < 8; ++i)
#pragma unroll
                for (int j = 0; j < 8; ++j)
                    acc[i][j] = fmaf(a_[i], b_[j], acc[i][j]);
        }
        __syncthreads();
    }

    // per-row partial argmin over this 128-col stripe, shuffle-reduced over tx
#pragma unroll
    for (int hi = 0; hi < 2; ++hi) {
#pragma unroll
        for (int i = 0; i < 4; ++i) {
            const int rl = hi*64 + ty*4 + i;
            const float zr = zn2[m0 + rl];
            float best = 3.4e38f; int bi = 0x7fffffff;
#pragma unroll
            for (int hj = 0; hj < 2; ++hj) {
#pragma unroll
                for (int j = 0; j < 4; ++j) {
                    const int col = n0 + hj*64 + tx*4 + j;
                    const float t1 = zr + cn2[col];
                    const float d  = t1 - 2.0f * acc[hi*4+i][hj*4+j];
                    if (d < best) { best = d; bi = col; }
                }
            }
#pragma unroll
            for (int off = 1; off < 16; off <<= 1) {
                const float ov = __shfl_xor(best, off);
                const int   oi = __shfl_xor(bi, off);
                if (ov < best || (ov == best && oi < bi)) { best = ov; bi = oi; }
            }
            if (tx == 0) {
                PV[(size_t)(m0 + rl) * 4 + blockIdx.x] = best;
                PI[(size_t)(m0 + rl) * 4 + blockIdx.x] = bi;
            }
        }
    }
}

__global__ void argmin_reduce(const float* __restrict__ PV, const int* __restrict__ PI,
                              int* __restrict__ assign)
{
    const int m = blockIdx.x * 256 + threadIdx.x;
    float best = PV[(size_t)m * 4]; int bi = PI[(size_t)m * 4];
#pragma unroll
    for (int nb = 1; nb < 4; ++nb) {
        const float v = PV[(size_t)m * 4 + nb]; const int ix = PI[(size_t)m * 4 + nb];
        if (v < best || (v == best && ix < bi)) { best = v; bi = ix; }
    }
    assign[m] = bi;
}

// ---------------- fused dense (64x256 tile, full width) + LayerNorm ----------
__global__ __launch_bounds__(256)
void dense_ln_kernel(const float* __restrict__ A, const float* __restrict__ Bw,
                     const float* __restrict__ bias, const float* __restrict__ gamma,
                     const float* __restrict__ beta, float* __restrict__ Z,
                     float* __restrict__ zn2)
{
    __shared__ float As[16][68];
    __shared__ float Bs[16][256];
    __shared__ float rred[64][17];
    __shared__ float rstat[64];
    const int tid = threadIdx.x, tx = tid & 15, ty = tid >> 4;
    const int m0 = blockIdx.x * 64;
    float acc[4][16];
#pragma unroll
    for (int i = 0; i < 4; ++i)
#pragma unroll
        for (int j = 0; j < 16; ++j) acc[i][j] = 0.f;

    const int ar = tid >> 2, ac = (tid & 3) * 4;
    const int br = tid >> 4, bc = (tid & 15) * 16;
    for (int kb = 0; kb < 256; kb += 16) {
        float4 a = *(const float4*)(A + (size_t)(m0 + ar) * 256 + kb + ac);
        As[ac+0][ar] = a.x; As[ac+1][ar] = a.y; As[ac+2][ar] = a.z; As[ac+3][ar] = a.w;
#pragma unroll
        for (int q = 0; q < 4; ++q)
            *(float4*)&Bs[br][bc + q*4] =
                *(const float4*)(Bw + (size_t)(kb + br) * 256 + bc + q*4);
        __syncthreads();
#pragma unroll
        for (int kk = 0; kk < 16; ++kk) {
            float4 a4 = *(const float4*)&As[kk][ty*4];
            float av[4] = {a4.x, a4.y, a4.z, a4.w};
            float bv[16];
#pragma unroll
            for (int q = 0; q < 4; ++q) {
                float4 b4 = *(const float4*)&Bs[kk][q*64 + tx*4];
                bv[q*4+0] = b4.x; bv[q*4+1] = b4.y; bv[q*4+2] = b4.z; bv[q*4+3] = b4.w;
            }
#pragma unroll
            for (int i = 0; i < 4; ++i)
#pragma unroll
                for (int j = 0; j < 16; ++j)
                    acc[i][j] = fmaf(av[i], bv[j], acc[i][j]);
        }
        __syncthreads();
    }

    float bcol[16];
#pragma unroll
    for (int q = 0; q < 4; ++q) {
        float4 b4 = *(const float4*)(bias + q*64 + tx*4);
        bcol[q*4+0] = b4.x; bcol[q*4+1] = b4.y; bcol[q*4+2] = b4.z; bcol[q*4+3] = b4.w;
    }
#pragma unroll
    for (int i = 0; i < 4; ++i)
#pragma unroll
        for (int j = 0; j < 16; ++j) acc[i][j] += bcol[j];

#pragma unroll
    for (int i = 0; i < 4; ++i) {
        float s = 0.f;
#pragma unroll
        for (int j = 0; j < 16; ++j) s += acc[i][j];
        rred[ty*4+i][tx] = s;
    }
    __syncthreads();
    if (tid < 64) {
        float s = 0.f;
#pragma unroll
        for (int t = 0; t < 16; ++t) s += rred[tid][t];
        rstat[tid] = s * (1.f / 256.f);
    }
    __syncthreads();
    float mean_[4];
#pragma unroll
    for (int i = 0; i < 4; ++i) mean_[i] = rstat[ty*4+i];

#pragma unroll
    for (int i = 0; i < 4; ++i) {
        float s = 0.f;
#pragma unroll
        for (int j = 0; j < 16; ++j) { float d = acc[i][j] - mean_[i]; s += d * d; }
        rred[ty*4+i][tx] = s;
    }
    __syncthreads();
    if (tid < 64) {
        float s = 0.f;
#pragma unroll
        for (int t = 0; t < 16; ++t) s += rred[tid][t];
        rstat[tid] = s * (1.f / 256.f);
    }
    __syncthreads();
    float rstd_[4];
#pragma unroll
    for (int i = 0; i < 4; ++i) rstd_[i] = sqrtf(rstat[ty*4+i] + 1e-5f);

    float gam[16], bet[16];
#pragma unroll
    for (int q = 0; q < 4; ++q) {
        float4 g4 = *(const float4*)(gamma + q*64 + tx*4);
        float4 e4 = *(const float4*)(beta  + q*64 + tx*4);
        gam[q*4+0] = g4.x; gam[q*4+1] = g4.y; gam[q*4+2] = g4.z; gam[q*4+3] = g4.w;
        bet[q*4+0] = e4.x; bet[q*4+1] = e4.y; bet[q*4+2] = e4.z; bet[q*4+3] = e4.w;
    }
#pragma unroll
    for (int i = 0; i < 4; ++i)
#pragma unroll
        for (int j = 0; j < 16; ++j) {
            const float d = acc[i][j] - mean_[i];
            acc[i][j] = gam[j] * (d / rstd_[i]) + bet[j];
        }

#pragma unroll
    for (int i = 0; i < 4; ++i) {
        float s = 0.f;
#pragma unroll
        for (int j = 0; j < 16; ++j) s += acc[i][j] * acc[i][j];
        rred[ty*4+i][tx] = s;
    }
    __syncthreads();
    if (tid < 64) {
        float s = 0.f;
#pragma unroll
        for (int t = 0; t < 16; ++t) s += rred[tid][t];
        zn2[m0 + tid] = s;
    }

#pragma unroll
    for (int i = 0; i < 4; ++i) {
        const int row = m0 + ty*4 + i;
#pragma unroll
        for (int q = 0; q < 4; ++q) {
            float4 v;
            v.x = acc[i][q*4+0]; v.y = acc[i][q*4+1];
            v.z = acc[i][q*4+2]; v.w = acc[i][q*4+3];
            *(float4*)(Z + (size_t)row * 256 + q*64 + tx*4) = v;
        }
    }
}

// ---------------- small GEMM: 64x64 tiles -----------------------------------
// TRA=0: A is (M,Kd).  TRA=1: A is (Kd,M) (Out = A^T B).  B is (Kd,N).
// EPI: 0 none; 1: 2*E - acc; 2: I - acc; 3: acc + I; 4: diversity partials
template<int TRA, int EPI>
__global__ __launch_bounds__(256)
void small_gemm(const float* __restrict__ A, const float* __restrict__ B,
                const float* __restrict__ E, float* __restrict__ Out,
                int M, int N, int Kd,
                const float* __restrict__ cn2, float* __restrict__ divPart)
{
    __shared__ float As[16][68];
    __shared__ float Bs[16][68];
    __shared__ float red2[256];
    const int tid = threadIdx.x;
    const int tx = tid & 15, ty = tid >> 4;
    const int n0 = blockIdx.x * 64, m0 = blockIdx.y * 64;
    float acc[4][4];
#pragma unroll
    for (int i = 0; i < 4; ++i)
#pragma unroll
        for (int j = 0; j < 4; ++j) acc[i][j] = 0.f;

    for (int kb = 0; kb < Kd; kb += 16) {
        if (TRA == 0) {
            const int ar2 = tid >> 2, ac2 = (tid & 3) * 4;
            float4 a = *(const float4*)(A + (size_t)(m0 + ar2) * Kd + kb + ac2);
            As[ac2+0][ar2] = a.x; As[ac2+1][ar2] = a.y;
            As[ac2+2][ar2] = a.z; As[ac2+3][ar2] = a.w;
        } else {
            const int ar2 = tid >> 4, ac2 = (tid & 15) * 4;
            float4 a = *(const float4*)(A + (size_t)(kb + ar2) * M + m0 + ac2);
            *(float4*)&As[ar2][ac2] = a;
        }
        {
            const int br2 = tid >> 4, bc2 = (tid & 15) * 4;
            float4 b = *(const float4*)(B + (size_t)(kb + br2) * N + n0 + bc2);
            *(float4*)&Bs[br2][bc2] = b;
        }
        __syncthreads();
#pragma unroll
        for (int kk = 0; kk < 16; ++kk) {
            float4 a4 = *(const float4*)&As[kk][ty*4];
            float4 b4 = *(const float4*)&Bs[kk][tx*4];
            float a_[4] = {a4.x, a4.y, a4.z, a4.w};
            float b_[4] = {b4.x, b4.y, b4.z, b4.w};
#pragma unroll
            for (int i = 0; i < 4; ++i)
#pragma unroll
                for (int j = 0; j < 4; ++j)
                    acc[i][j] = fmaf(a_[i], b_[j], acc[i][j]);
        }
        __syncthreads();
    }
    if (EPI == 4) {
        float dsum = 0.f;
#pragma unroll
        for (int i = 0; i < 4; ++i) {
            const int row = m0 + ty*4 + i;
            const float ri = 1.f / sqrtf(fmaxf(cn2[row], 1e-12f));
#pragma unroll
            for (int j = 0; j < 4; ++j) {
                const int col = n0 + tx*4 + j;
                if (row != col) {
                    const float rj = 1.f / sqrtf(fmaxf(cn2[col], 1e-12f));
                    dsum += fmaxf(acc[i][j] * ri * rj, 0.f);
                }
            }
        }
        red2[tid] = dsum;
        __syncthreads();
        for (int s = 128; s > 0; s >>= 1) {
            if (tid < s) red2[tid] += red2[tid + s];
            __syncthreads();
        }
        if (tid == 0) divPart[blockIdx.y * gridDim.x + blockIdx.x] = red2[0];
        return;
    }
#pragma unroll
    for (int i = 0; i < 4; ++i) {
        const int row = m0 + ty*4 + i;
#pragma unroll
        for (int j = 0; j < 4; ++j) {
            const int col = n0 + tx*4 + j;
            float v = acc[i][j];
            if (EPI == 1) v = 2.f * E[(size_t)row * N + col] - v;
            else if (EPI == 2) v = ((row == col) ? 1.f : 0.f) - v;
            else if (EPI == 3) v = v + ((row == col) ? 1.f : 0.f);
            Out[(size_t)row * N + col] = v;
        }
    }
}

// ---------------- Ct = C^T ; column norms of C -------------------------------
__global__ void transpose_ct(const float* __restrict__ C, float* __restrict__ Ct)
{
    const int idx = blockIdx.x * 256 + threadIdx.x;
    const int k = idx >> 8, d = idx & 255;
    Ct[idx] = C[(size_t)d * K_ + k];
}

__global__ void cn2_kernel(const float* __restrict__ C, float* __restrict__ cn2)
{
    const int k = blockIdx.x * 256 + threadIdx.x;
    float s = 0.f;
    for (int d = 0; d < D_; ++d) { float c = C[(size_t)d * K_ + k]; s = fmaf(c, c, s); }
    cn2[k] = s;
}

// ------------- ||S||_inf (via symmetry: column sums) -> X0 = c*I -------------
__global__ void scal_init_kernel(const float* __restrict__ S, float* __restrict__ X)
{
    __shared__ float red[256];
    const int t = threadIdx.x;
    float s = 0.f;
    for (int q = 0; q < D_; ++q) s += fabsf(S[(size_t)q * D_ + t]);
    red[t] = s; __syncthreads();
    for (int sh = 128; sh > 0; sh >>= 1) {
        if (t < sh) red[t] = fmaxf(red[t], red[t + sh]);
        __syncthreads();
    }
    const float c = 2.f / (1.f + red[0]);
    for (int idx = t; idx < D_ * D_; idx += 256) {
        const int i = idx >> 8, j = idx & 255;
        X[idx] = (i == j) ? c : 0.f;
    }
}

// ---------------- simplex projection, Michelot, one wave per row -------------
__global__ __launch_bounds__(256)
void project_kernel(float* P)
{
    const int wave = threadIdx.x >> 6;
    const int lane = threadIdx.x & 63;
    const int row = blockIdx.x * 4 + wave;
    const size_t base = (size_t)row * K_ + lane;
    float v[8];
#pragma unroll
    for (int j = 0; j < 8; ++j) v[j] = P[base + j * 64];

    float s = 0.f;
#pragma unroll
    for (int j = 0; j < 8; ++j) s += v[j];
    for (int off = 32; off > 0; off >>= 1) s += __shfl_xor(s, off);

    float theta = (s - 1.f) * (1.f / 512.f);
    int cnt = K_;
    for (int it = 0; it < K_; ++it) {
        float ls = 0.f; int lc = 0;
#pragma unroll
        for (int j = 0; j < 8; ++j)
            if (v[j] > theta) { ls += v[j]; ++lc; }
        for (int off = 32; off > 0; off >>= 1) {
            ls += __shfl_xor(ls, off);
            lc += __shfl_xor(lc, off);
        }
        if (lc == cnt) break;
        theta = (ls - 1.f) / (float)lc;
        cnt = lc;
    }
#pragma unroll
    for (int j = 0; j < 8; ++j) P[base + j * 64] = fmaxf(v[j] - theta, 0.f);
}

// ---------------- column partial sums of P (for p_j) -------------------------
__global__ __launch_bounds__(512)
void colsum_kernel(const float* __restrict__ P, float* __restrict__ part)
{
    const int k = threadIdx.x;
    const int b = blockIdx.x;
    float s = 0.f;
    const size_t base = (size_t)b * 128 * K_ + k;
    for (int r = 0; r < 128; ++r) s += P[base + (size_t)r * K_];
    part[(size_t)b * K_ + k] = s;
}

// ---------------- finalize (slim): scalars only ------------------------------
#define BLOCK_REDUCE_512(val, result) \
    red[t] = (val); __syncthreads(); \
    for (int s_ = 256; s_ > 0; s_ >>= 1) { if (t < s_) red[t] += red[t + s_]; __syncthreads(); } \
    result = red[0]; __syncthreads();

__global__ __launch_bounds__(512)
void finalize_kernel(const float* __restrict__ part, const float* __restrict__ divPart,
                     const float* __restrict__ lossPart, float* __restrict__ out_scal)
{
    __shared__ float red[512];
    const int t = threadIdx.x;

    float praw = 0.f;
    for (int b = 0; b < 256; ++b) praw += part[b * K_ + t];
    const float pm = praw * (1.f / 32768.f);

    const float pj = fminf(fmaxf(pm, 1e-10f), 1.0f);
    float sp; BLOCK_REDUCE_512(pj, sp);
    const float pjn = pj / sp;
    float Hbits; BLOCK_REDUCE_512(-pjn * logf(pjn) / 0.69314718056f, Hbits);

    float spm; BLOCK_REDUCE_512(pm, spm);
    const float s2 = spm + 1e-5f;
    const float pmn = pm / s2;
    float ereg; BLOCK_REDUCE_512(-pmn * logf(pmn + 1e-5f), ereg);

    float dv = (t < 64) ? divPart[t] : 0.f;
    float divs; BLOCK_REDUCE_512(dv, divs);
    const float divloss = divs * (1.f / 262144.f);

    float lp = lossPart[t];
    float prim; BLOCK_REDUCE_512(lp, prim);
    prim *= 1.f / 8388608.f;

    if (t == 0) {
        out_scal[0] = prim + 0.5f * ereg + 0.5f * divloss;
        out_scal[1] = exp2f(Hbits);
    }
}

// ---------------- launch -----------------------------------------------------
extern "C" void kernel_launch(void* const* d_in, const int* in_sizes, int n_in,
                              void* d_out, int out_size, void* d_ws, size_t ws_size,
                              hipStream_t stream)
{
    const float* inputs = (const float*)d_in[0];
    const float* gamma  = (const float*)d_in[1];
    const float* beta   = (const float*)d_in[2];
    const float* C      = (const float*)d_in[3];   // (D,K)
    const float* d_w    = (const float*)d_in[4];   // (D,D)
    const float* d_b    = (const float*)d_in[5];   // (D,)

    float* out = (float*)d_out;
    float* Z = out;                                 // M*D slot (Z, later Zq)
    float* P = out + (size_t)M_ * D_;               // M*K slot (P_sol -> P_proj)
    float* out_scal = P + (size_t)M_ * K_;          // loss, perplexity

    float* w = (float*)d_ws;
    float* Smat = w;     w += D_ * D_;
    float* Xa   = w;     w += D_ * D_;
    float* Xb   = w;     w += D_ * D_;
    float* Tb   = w;     w += D_ * D_;
    float* Ut   = w;     w += K_ * D_;              // C^T Sinv  (512x256)
    float* Ainv = w;     w += K_ * K_;
    float* Ct   = w;     w += K_ * D_;
    float* cn2  = w;     w += K_;
    float* zn2  = w;     w += M_;
    float* part = w;     w += 256 * K_;
    float* lossPart = w; w += 512;
    float* divPart  = w; w += 64;
    float* PV   = w;     w += M_ * 4;
    int* PI     = (int*)w; w += M_ * 4;
    int* assign = (int*)w;

    // 1. Z = LN(inputs @ d_w + d_b), zn2    (f32, argmin-critical)
    dense_ln_kernel<<<M_/64, 256, 0, stream>>>(inputs, d_w, d_b, gamma, beta, Z, zn2);
    // 2. C^T and column norms
    transpose_ct<<<(K_ * D_) / 256, 256, 0, stream>>>(C, Ct);
    cn2_kernel<<<K_ / 256, 256, 0, stream>>>(C, cn2);
    // 3. S = C C^T + I
    small_gemm<1, 3><<<dim3(D_/64, D_/64), 256, 0, stream>>>(Ct, Ct, nullptr, Smat, D_, D_, K_, nullptr, nullptr);
    // 4. NS init
    scal_init_kernel<<<1, 256, 0, stream>>>(Smat, Xa);
    // 5. Newton-Schulz x6: X <- 2X - X S X
    float* Xc = Xa; float* Xn = Xb;
    for (int it = 0; it < 6; ++it) {
        small_gemm<0, 0><<<dim3(D_/64, D_/64), 256, 0, stream>>>(Smat, Xc, nullptr, Tb, D_, D_, D_, nullptr, nullptr);
        small_gemm<0, 1><<<dim3(D_/64, D_/64), 256, 0, stream>>>(Xc, Tb, Xc, Xn, D_, D_, D_, nullptr, nullptr);
        float* tmp = Xc; Xc = Xn; Xn = tmp;
    }
    // 6. Ut = C^T Sinv ; Ainv = I - Ut C ; diversity partials from C^T C
    small_gemm<1, 0><<<dim3(D_/64, K_/64), 256, 0, stream>>>(C, Xc, nullptr, Ut, K_, D_, D_, nullptr, nullptr);
    small_gemm<0, 2><<<dim3(K_/64, K_/64), 256, 0, stream>>>(Ut, C, nullptr, Ainv, K_, K_, D_, nullptr, nullptr);
    small_gemm<1, 4><<<dim3(K_/64, K_/64), 256, 0, stream>>>(C, C, nullptr, nullptr, K_, K_, D_, cn2, divPart);
    // 7. scores = Z @ C (f32) with fused partial argmin -> assign
    score_argmin_gemm<<<dim3(K_/128, M_/128), 256, 0, stream>>>(Z, C, cn2, zn2, PV, PI);
    argmin_reduce<<<M_/256, 256, 0, stream>>>(PV, PI, assign);
    // 8. P_sol^T = Z @ Ut^T + Ainv[assign,:]   (split-bf16 MFMA)
    mfma_gemm<2><<<dim3(K_/128, M_/128), 256, 0, stream>>>(
        Z, Ut, P, D_, K_, Ainv, assign, nullptr, nullptr);
    // 9. simplex projection in place
    project_kernel<<<M_/4, 256, 0, stream>>>(P);
    // 10. column partial sums
    colsum_kernel<<<256, 512, 0, stream>>>(P, part);
    // 11. Zq = P @ C^T (split-bf16 MFMA; B^T = C), loss partials
    mfma_gemm<3><<<dim3(D_/128, M_/128), 256, 0, stream>>>(
        P, C, Z, K_, D_, nullptr, nullptr, Z, lossPart);
    // 12. scalars
    finalize_kernel<<<1, 512, 0, stream>>>(part, divPart, lossPart, out_scal);

    (void)in_sizes; (void)n_in; (void)out_size; (void)ws_size;
}